// Round 12
// baseline (177.528 us; speedup 1.0000x reference)
//
#include <hip/hip_runtime.h>
#include <stdint.h>

#define EPSF 1e-5f
#define LOG2E 1.4426950408889634f

typedef float f32x2 __attribute__((ext_vector_type(2)));
typedef float f32x4 __attribute__((ext_vector_type(4)));
typedef _Float16 h2 __attribute__((ext_vector_type(2)));
union UH2 { uint32_t u; h2 h; };

__device__ __forceinline__ uint32_t pkh(float a, float b){
  UH2 c; c.h.x = (_Float16)a; c.h.y = (_Float16)b; return c.u;
}
__device__ __forceinline__ h2 ash2(uint32_t u){ UH2 c; c.u = u; return c.h; }
__device__ __forceinline__ uint32_t padd16(uint32_t a, uint32_t b){
  UH2 c; c.h = ash2(a) + ash2(b); return c.u;          // v_pk_add_f16
}
#if __has_builtin(__builtin_amdgcn_fdot2)
__device__ __forceinline__ float fdot2u(uint32_t a, uint32_t b, float c){
  return __builtin_amdgcn_fdot2(ash2(a), ash2(b), c, false);
}
#else
__device__ __forceinline__ float fdot2u(uint32_t a, uint32_t b, float c){
  h2 x = ash2(a), y = ash2(b);
  return fmaf((float)x.y, (float)y.y, fmaf((float)x.x, (float)y.x, c));
}
#endif

// ---------------- conv1 + bn + relu (+ relpack tail blocks, f16 tables) ----------------
__global__ __launch_bounds__(256)
void k_conv1(const float* __restrict__ in, const float* __restrict__ w,
             const float* __restrict__ bn, float* __restrict__ out,
             const float* __restrict__ relH, const float* __restrict__ relW,
             uint4* __restrict__ rqkH, uint4* __restrict__ rveH,
             uint4* __restrict__ rqkW, uint4* __restrict__ rveW) {
  if (blockIdx.x >= 512) {
    int which = blockIdx.x - 512;
    int NJ = which ? 255 : 511;
    const float* rel = which ? relW : relH;
    uint4* rqk = which ? rqkW : rqkH;
    uint4* rve = which ? rveW : rveH;
    const float* q = rel;
    const float* k = rel + 4*NJ;
    const float* v = rel + 8*NJ;
    for (int j = threadIdx.x; j < NJ; j += 256) {
      int jr = NJ-1-j;
      uint4 a;
      a.x = pkh(q[0*NJ+j], q[1*NJ+j]);
      a.y = pkh(q[2*NJ+j], q[3*NJ+j]);
      a.z = pkh(k[0*NJ+jr], k[1*NJ+jr]);
      a.w = pkh(k[2*NJ+jr], k[3*NJ+jr]);
      rqk[j] = a;
      uint4 b;
      b.x = pkh(v[0*NJ+j], v[1*NJ+j]);
      b.y = pkh(v[2*NJ+j], v[3*NJ+j]);
      b.z = pkh(v[4*NJ+j], v[5*NJ+j]);
      b.w = pkh(v[6*NJ+j], v[7*NJ+j]);
      rve[j] = b;
    }
    return;
  }
  __shared__ float L[64*65];
  int tid = threadIdx.x;
  int p0 = blockIdx.x * 64;
  int lane = tid & 63;
  int wvs = __builtin_amdgcn_readfirstlane(tid >> 6);
  #pragma unroll
  for (int rr = 0; rr < 16; ++rr) {
    int c = wvs*16 + rr;
    L[lane*65 + c] = in[(size_t)c*32768 + p0 + lane];
  }
  __syncthreads();
  f32x2 xv2[32];
  #pragma unroll
  for (int c2 = 0; c2 < 32; ++c2) {
    xv2[c2].x = L[lane*65 + 2*c2];
    xv2[c2].y = L[lane*65 + 2*c2 + 1];
  }
  float val[16];
  #pragma unroll
  for (int r = 0; r < 16; ++r) {
    int o = wvs*16 + r;
    const f32x2* wr = (const f32x2*)(w + o*64);
    f32x2 a2 = {0.f, 0.f};
    #pragma unroll
    for (int c2 = 0; c2 < 32; ++c2) a2 = wr[c2]*xv2[c2] + a2;
    float acc = a2.x + a2.y;
    float s = bn[o] * rsqrtf(bn[192+o] + EPSF);
    val[r] = fmaxf(fmaf(acc, s, fmaf(-bn[128+o], s, bn[64+o])), 0.f);
  }
  __syncthreads();
  #pragma unroll
  for (int r = 0; r < 16; ++r) L[lane*65 + wvs*16 + r] = val[r];
  __syncthreads();
  float4* dst = (float4*)(out + (size_t)p0*64);
  #pragma unroll
  for (int k = 0; k < 4; ++k) {
    int f4 = tid + k*256;
    int f = f4*4; int p = f >> 6, o = f & 63;
    float4 v;
    v.x = L[p*65+o]; v.y = L[p*65+o+1]; v.z = L[p*65+o+2]; v.w = L[p*65+o+3];
    dst[f4] = v;
  }
}

// ---------------- kqv projection + bn -> f16 K/V + f32 Q ----------------
template<int LEN, int RS, int CS>
__global__ __launch_bounds__(512)
void k_kqv(const float* __restrict__ in, const float* __restrict__ w,
           const float* __restrict__ bn, uint4* __restrict__ kvV,
           uint2* __restrict__ kvK, float* __restrict__ qb) {
  __shared__ float L[64*65];
  int tid = threadIdx.x;
  int n = blockIdx.x;
  int y0 = blockIdx.y * 64;
  #pragma unroll
  for (int rr = 0; rr < 8; ++rr) {
    int idx = tid + rr*512;
    int yy = idx >> 6, c = idx & 63;
    L[yy*65 + c] = in[((size_t)(y0+yy)*RS + (size_t)n*CS)*64 + c];
  }
  __syncthreads();
  int hd = __builtin_amdgcn_readfirstlane(tid >> 6);
  int yy = tid & 63;
  f32x2 xv2[32];
  #pragma unroll
  for (int c2 = 0; c2 < 32; ++c2) {
    xv2[c2].x = L[yy*65 + 2*c2];
    xv2[c2].y = L[yy*65 + 2*c2 + 1];
  }
  float val[16];
  #pragma unroll
  for (int r = 0; r < 16; ++r) {
    int o = hd*16 + r;
    const f32x2* wr = (const f32x2*)(w + o*64);
    f32x2 a2 = {0.f, 0.f};
    #pragma unroll
    for (int c2 = 0; c2 < 32; ++c2) a2 = wr[c2]*xv2[c2] + a2;
    float acc = a2.x + a2.y;
    float s = bn[o] * rsqrtf(bn[384+o] + EPSF);
    val[r] = fmaf(acc, s, fmaf(-bn[256+o], s, bn[128+o]));
  }
  size_t base = ((size_t)n*8 + hd)*LEN + (y0 + yy);
  kvK[base] = make_uint2(pkh(val[0],val[1]), pkh(val[2],val[3]));
  kvV[base] = make_uint4(pkh(val[8],val[9]),  pkh(val[10],val[11]),
                         pkh(val[12],val[13]), pkh(val[14],val[15]));
  float4 qq; qq.x = val[4]; qq.y = val[5]; qq.z = val[6]; qq.w = val[7];
  *(float4*)(qb + base*4) = qq;
}

// ---------------- axial attention core (v12: f16 dot2/fma_mix, windowed) ----------------
// logit2 = kt.(q + ke'') + q.qe'; kt=A0L*k, qe'=A1L*qe, ke''=(A2L/A0L)*ke (all f16)
__device__ __forceinline__ float pairA(uint32_t q01, uint32_t q23, uint4 e,
                                       uint32_t kt01, uint32_t kt23) {
  uint32_t t01 = padd16(q01, e.z);
  uint32_t t23 = padd16(q23, e.w);
  return fdot2u(kt01, t01, fdot2u(kt23, t23, fdot2u(q01, e.x, fdot2u(q23, e.y, 0.f))));
}
__device__ __forceinline__ void pairB(float e, uint4 ve, uint4 vv,
                                      float* A, float& ss) {
  ss += e;
  h2 w0 = ash2(vv.x) + ash2(ve.x);
  h2 w1 = ash2(vv.y) + ash2(ve.y);
  h2 w2 = ash2(vv.z) + ash2(ve.z);
  h2 w3 = ash2(vv.w) + ash2(ve.w);
  A[0] = fmaf((float)w0.x, e, A[0]);   // v_fma_mix_f32: f32 acc, exact
  A[1] = fmaf((float)w0.y, e, A[1]);
  A[2] = fmaf((float)w1.x, e, A[2]);
  A[3] = fmaf((float)w1.y, e, A[3]);
  A[4] = fmaf((float)w2.x, e, A[4]);
  A[5] = fmaf((float)w2.y, e, A[5]);
  A[6] = fmaf((float)w3.x, e, A[6]);
  A[7] = fmaf((float)w3.y, e, A[7]);
}

// Block = (n-block of NB, head). T = NB*(LEN/4)*G threads.
template<int LEN, int NB, int G, bool RELUO, int XS, int NS>
__device__ __forceinline__
void attn_body(const uint4* __restrict__ kvV, const uint2* __restrict__ kvK,
               const float* __restrict__ qb, const uint4* __restrict__ rqk,
               const uint4* __restrict__ rve, const float* __restrict__ lbn,
               float* __restrict__ out) {
  constexpr int NJ = 2*LEN-1;
  constexpr int NJ4 = (NJ+1)/4;
  constexpr int XT = LEN/4;
  constexpr int T = NB*XT*G;
  constexpr int YR = LEN/G;
  constexpr size_t S1 = (size_t)NB*LEN*24 + (size_t)NJ4*4*16*2;
  constexpr size_t S2 = (size_t)(G-1)*NB*LEN*40;
  constexpr size_t PS = S1 > S2 ? S1 : S2;
  int nb = blockIdx.x >> 3;
  int hd = blockIdx.x & 7;
  int n0 = nb * NB;
  int t  = threadIdx.x;

  __shared__ __align__(16) char pool[PS];
  uint2* sKt = (uint2*)(pool);                                // [NB*LEN] kt f16
  uint4* sV2 = (uint4*)(pool + (size_t)NB*LEN*8);             // [NB*LEN] v f16
  uint4* tQK = (uint4*)(pool + (size_t)NB*LEN*24);            // [4][NJ4]
  uint4* tVE = (uint4*)(pool + (size_t)NB*LEN*24 + (size_t)NJ4*64); // [4][NJ4]

  float A0L, A1L, A2L;
  {
    int c0 = hd, c1 = 8+hd, c2 = 16+hd;
    A0L = lbn[c0]*rsqrtf(lbn[72+c0]+EPSF)*LOG2E;
    A1L = lbn[c1]*rsqrtf(lbn[72+c1]+EPSF)*LOG2E;
    A2L = lbn[c2]*rsqrtf(lbn[72+c2]+EPSF)*LOG2E;
  }
  float A0g = (fabsf(A0L) > 1e-25f) ? A0L : copysignf(1e-25f, A0L);
  float ratio = A2L / A0g;

  for (int i = t; i < NB*LEN; i += T) {
    int nn = i / LEN, yy = i % LEN;
    size_t src = ((size_t)(n0+nn)*8 + hd)*LEN + yy;
    uint2 kk = kvK[src];
    h2 a = ash2(kk.x), b = ash2(kk.y);
    sKt[i] = make_uint2(pkh(A0g*(float)a.x, A0g*(float)a.y),
                        pkh(A0g*(float)b.x, A0g*(float)b.y));
    sV2[i] = kvV[src];
  }
  for (int j = t; j < NJ; j += T) {
    uint4 a = rqk[j];
    h2 q01 = ash2(a.x), q23 = ash2(a.y), k01 = ash2(a.z), k23 = ash2(a.w);
    uint4 sq;
    sq.x = pkh(A1L*(float)q01.x,   A1L*(float)q01.y);
    sq.y = pkh(A1L*(float)q23.x,   A1L*(float)q23.y);
    sq.z = pkh(ratio*(float)k01.x, ratio*(float)k01.y);
    sq.w = pkh(ratio*(float)k23.x, ratio*(float)k23.y);
    int r = j & 3, mm = j >> 2;
    tQK[r*NJ4 + mm] = sq;
    tVE[r*NJ4 + mm] = rve[j];
  }

  int g  = t / (NB*XT);
  int u  = t % (NB*XT);
  int ni = u / XT;
  int tl = u % XT;
  int y0 = g * YR;
  int x0 = 4 * tl;
  int niL = ni * LEN;
  size_t kb = ((size_t)(n0+ni)*8 + hd)*LEN;

  uint32_t q01[4], q23[4];
  #pragma unroll
  for (int i = 0; i < 4; ++i) {
    f32x4 qq = *(const f32x4*)(qb + (kb + x0 + i)*4);
    q01[i] = pkh(qq.x, qq.y);
    q23[i] = pkh(qq.z, qq.w);
  }

  float m[4], ss[4], acc[4][8];
  #pragma unroll
  for (int i=0;i<4;++i){ m[i]=-3.0e38f; ss[i]=0.f;
    #pragma unroll
    for(int d=0;d<8;++d) acc[i][d]=0.f; }

  __syncthreads();

  // window prologue: (y0 + LEN-1) & 3 == 3 always (y0, x0 mult of 4)
  int mi = ((y0 + LEN-1) >> 2) - (x0 >> 2);
  uint4 Wq0 = tQK[0*NJ4 + mi], Wq1 = tQK[1*NJ4 + mi], Wq2 = tQK[2*NJ4 + mi];
  uint4 Wv0 = tVE[0*NJ4 + mi], Wv1 = tVE[1*NJ4 + mi], Wv2 = tVE[2*NJ4 + mi];

  for (int cc = 0; cc < YR/4; ++cc) {
    int yb = niL + y0 + 4*cc;
    int ma = mi + cc;
    int mb = ma + 1;
    float lr[4][4];
    // ---- pass A (parities 3,0,1,2) ----
    uint4 E3 = tQK[3*NJ4 + ma];
    { uint2 kt = sKt[yb];
      lr[0][0]=pairA(q01[0],q23[0],E3, kt.x,kt.y); lr[1][0]=pairA(q01[1],q23[1],Wq2,kt.x,kt.y);
      lr[2][0]=pairA(q01[2],q23[2],Wq1,kt.x,kt.y); lr[3][0]=pairA(q01[3],q23[3],Wq0,kt.x,kt.y); }
    uint4 E0 = tQK[0*NJ4 + mb];
    { uint2 kt = sKt[yb+1];
      lr[0][1]=pairA(q01[0],q23[0],E0, kt.x,kt.y); lr[1][1]=pairA(q01[1],q23[1],E3, kt.x,kt.y);
      lr[2][1]=pairA(q01[2],q23[2],Wq2,kt.x,kt.y); lr[3][1]=pairA(q01[3],q23[3],Wq1,kt.x,kt.y); }
    uint4 E1 = tQK[1*NJ4 + mb];
    { uint2 kt = sKt[yb+2];
      lr[0][2]=pairA(q01[0],q23[0],E1, kt.x,kt.y); lr[1][2]=pairA(q01[1],q23[1],E0, kt.x,kt.y);
      lr[2][2]=pairA(q01[2],q23[2],E3, kt.x,kt.y); lr[3][2]=pairA(q01[3],q23[3],Wq2,kt.x,kt.y); }
    uint4 E2 = tQK[2*NJ4 + mb];
    { uint2 kt = sKt[yb+3];
      lr[0][3]=pairA(q01[0],q23[0],E2, kt.x,kt.y); lr[1][3]=pairA(q01[1],q23[1],E1, kt.x,kt.y);
      lr[2][3]=pairA(q01[2],q23[2],E0, kt.x,kt.y); lr[3][3]=pairA(q01[3],q23[3],E3, kt.x,kt.y); }
    Wq0 = E0; Wq1 = E1; Wq2 = E2;
    // ---- chunk rescale, skipped when no lane's max grew (exact) ----
    float cm[4];
    bool need = false;
    #pragma unroll
    for (int i = 0; i < 4; ++i) {
      cm[i] = fmaxf(fmaxf(lr[i][0], lr[i][1]), fmaxf(lr[i][2], lr[i][3]));
      need = need || (cm[i] > m[i]);
    }
    if (__any(need)) {
      #pragma unroll
      for (int i = 0; i < 4; ++i) {
        float mn = fmaxf(m[i], cm[i]);
        float sc = __builtin_amdgcn_exp2f(m[i] - mn);
        m[i] = mn; ss[i] *= sc;
        #pragma unroll
        for (int d = 0; d < 8; ++d) acc[i][d] *= sc;
      }
    }
    // ---- pass B (same window schedule) ----
    uint4 F3 = tVE[3*NJ4 + ma];
    { uint4 vv = sV2[yb];
      pairB(__builtin_amdgcn_exp2f(lr[0][0]-m[0]), F3,  vv, acc[0], ss[0]);
      pairB(__builtin_amdgcn_exp2f(lr[1][0]-m[1]), Wv2, vv, acc[1], ss[1]);
      pairB(__builtin_amdgcn_exp2f(lr[2][0]-m[2]), Wv1, vv, acc[2], ss[2]);
      pairB(__builtin_amdgcn_exp2f(lr[3][0]-m[3]), Wv0, vv, acc[3], ss[3]); }
    uint4 F0 = tVE[0*NJ4 + mb];
    { uint4 vv = sV2[yb+1];
      pairB(__builtin_amdgcn_exp2f(lr[0][1]-m[0]), F0,  vv, acc[0], ss[0]);
      pairB(__builtin_amdgcn_exp2f(lr[1][1]-m[1]), F3,  vv, acc[1], ss[1]);
      pairB(__builtin_amdgcn_exp2f(lr[2][1]-m[2]), Wv2, vv, acc[2], ss[2]);
      pairB(__builtin_amdgcn_exp2f(lr[3][1]-m[3]), Wv1, vv, acc[3], ss[3]); }
    uint4 F1 = tVE[1*NJ4 + mb];
    { uint4 vv = sV2[yb+2];
      pairB(__builtin_amdgcn_exp2f(lr[0][2]-m[0]), F1,  vv, acc[0], ss[0]);
      pairB(__builtin_amdgcn_exp2f(lr[1][2]-m[1]), F0,  vv, acc[1], ss[1]);
      pairB(__builtin_amdgcn_exp2f(lr[2][2]-m[2]), F3,  vv, acc[2], ss[2]);
      pairB(__builtin_amdgcn_exp2f(lr[3][2]-m[3]), Wv2, vv, acc[3], ss[3]); }
    uint4 F2 = tVE[2*NJ4 + mb];
    { uint4 vv = sV2[yb+3];
      pairB(__builtin_amdgcn_exp2f(lr[0][3]-m[0]), F2,  vv, acc[0], ss[0]);
      pairB(__builtin_amdgcn_exp2f(lr[1][3]-m[1]), F1,  vv, acc[1], ss[1]);
      pairB(__builtin_amdgcn_exp2f(lr[2][3]-m[2]), F0,  vv, acc[2], ss[2]);
      pairB(__builtin_amdgcn_exp2f(lr[3][3]-m[3]), F3,  vv, acc[3], ss[3]); }
    Wv0 = F0; Wv1 = F1; Wv2 = F2;
  }

  // ---- one-shot G-way merge via LDS ----
  __syncthreads();
  float4* M0 = (float4*)(pool);
  float4* M1 = (float4*)(pool + (size_t)(G-1)*NB*LEN*16);
  float2* MS = (float2*)(pool + (size_t)(G-1)*NB*LEN*32);
  int xb = niL + x0;
  if (g > 0) {
    #pragma unroll
    for (int i = 0; i < 4; ++i) {
      int slot = (g-1)*NB*LEN + xb + i;
      M0[slot] = make_float4(acc[i][0],acc[i][1],acc[i][2],acc[i][3]);
      M1[slot] = make_float4(acc[i][4],acc[i][5],acc[i][6],acc[i][7]);
      MS[slot] = make_float2(m[i], ss[i]);
    }
  }
  __syncthreads();
  if (g == 0) {
    #pragma unroll
    for (int i = 0; i < 4; ++i) {
      float M = m[i];
      float2 oms[G-1];
      #pragma unroll
      for (int gg = 1; gg < G; ++gg) {
        oms[gg-1] = MS[(gg-1)*NB*LEN + xb + i];
        M = fmaxf(M, oms[gg-1].x);
      }
      float w0 = __builtin_amdgcn_exp2f(m[i] - M);
      float st = ss[i]*w0;
      float a[8];
      #pragma unroll
      for (int d = 0; d < 8; ++d) a[d] = acc[i][d]*w0;
      #pragma unroll
      for (int gg = 1; gg < G; ++gg) {
        int slot = (gg-1)*NB*LEN + xb + i;
        float wg = __builtin_amdgcn_exp2f(oms[gg-1].x - M);
        st += oms[gg-1].y*wg;
        float4 a0 = M0[slot];
        float4 a1 = M1[slot];
        a[0] = fmaf(a0.x, wg, a[0]); a[1] = fmaf(a0.y, wg, a[1]);
        a[2] = fmaf(a0.z, wg, a[2]); a[3] = fmaf(a0.w, wg, a[3]);
        a[4] = fmaf(a1.x, wg, a[4]); a[5] = fmaf(a1.y, wg, a[5]);
        a[6] = fmaf(a1.z, wg, a[6]); a[7] = fmaf(a1.w, wg, a[7]);
      }
      float inv = 1.0f / st;
      float* dst = out + ((size_t)(x0+i)*XS + (size_t)(n0+ni)*NS)*64 + hd*8;
      float4 lo, hi;
      lo.x = a[0]*inv; lo.y = a[1]*inv; lo.z = a[2]*inv; lo.w = a[3]*inv;
      hi.x = a[4]*inv; hi.y = a[5]*inv; hi.z = a[6]*inv; hi.w = a[7]*inv;
      if (RELUO) {
        lo.x=fmaxf(lo.x,0.f); lo.y=fmaxf(lo.y,0.f); lo.z=fmaxf(lo.z,0.f); lo.w=fmaxf(lo.w,0.f);
        hi.x=fmaxf(hi.x,0.f); hi.y=fmaxf(hi.y,0.f); hi.z=fmaxf(hi.z,0.f); hi.w=fmaxf(hi.w,0.f);
      }
      *(float4*)dst = lo;
      *((float4*)dst + 1) = hi;
    }
  }
}

// Distinct names so rocprof attributes H vs W separately.
__global__ __launch_bounds__(256, 2)
void k_attnH(const uint4* __restrict__ kvV, const uint2* __restrict__ kvK,
             const float* __restrict__ qb, const uint4* __restrict__ rqk,
             const uint4* __restrict__ rve, const float* __restrict__ lbn,
             float* __restrict__ out) {
  attn_body<256,1,4,false,128,1>(kvV, kvK, qb, rqk, rve, lbn, out);
}
__global__ __launch_bounds__(256, 2)
void k_attnW(const uint4* __restrict__ kvV, const uint2* __restrict__ kvK,
             const float* __restrict__ qb, const uint4* __restrict__ rqk,
             const uint4* __restrict__ rve, const float* __restrict__ lbn,
             float* __restrict__ out) {
  attn_body<128,2,4,true,1,128>(kvV, kvK, qb, rqk, rve, lbn, out);
}

// ---------------- conv3 + bn + residual + relu : NHWC in -> NCHW out ----------------
__global__ __launch_bounds__(256)
void k_conv3(const float* __restrict__ in, const float* __restrict__ w,
             const float* __restrict__ bn, const float* __restrict__ resid,
             float* __restrict__ out) {
  __shared__ float L[64*65];
  int tid = threadIdx.x;
  int p0 = blockIdx.x * 64;
  const float4* src = (const float4*)(in + (size_t)p0*64);
  #pragma unroll
  for (int k = 0; k < 4; ++k) {
    int f4 = tid + k*256;
    float4 v = src[f4];
    int f = f4*4; int p = f >> 6, o = f & 63;
    L[p*65+o] = v.x; L[p*65+o+1] = v.y; L[p*65+o+2] = v.z; L[p*65+o+3] = v.w;
  }
  __syncthreads();
  int lane = tid & 63;
  int wvs = __builtin_amdgcn_readfirstlane(tid >> 6);
  f32x2 xv2[32];
  #pragma unroll
  for (int c2 = 0; c2 < 32; ++c2) {
    xv2[c2].x = L[lane*65 + 2*c2];
    xv2[c2].y = L[lane*65 + 2*c2 + 1];
  }
  #pragma unroll
  for (int r = 0; r < 16; ++r) {
    int o = wvs*16 + r;
    const f32x2* wr = (const f32x2*)(w + o*64);
    f32x2 a2 = {0.f, 0.f};
    #pragma unroll
    for (int c2 = 0; c2 < 32; ++c2) a2 = wr[c2]*xv2[c2] + a2;
    float acc = a2.x + a2.y;
    float s = bn[o] * rsqrtf(bn[192+o] + EPSF);
    float val = fmaf(acc, s, fmaf(-bn[128+o], s, bn[64+o]));
    size_t idx = (size_t)o*32768 + p0 + lane;
    out[idx] = fmaxf(val + resid[idx], 0.f);
  }
}

extern "C" void kernel_launch(void* const* d_in, const int* in_sizes, int n_in,
                              void* d_out, int out_size, void* d_ws, size_t ws_size,
                              hipStream_t stream) {
  const float* x         = (const float*)d_in[0];
  const float* conv1_w   = (const float*)d_in[1];
  const float* bn1       = (const float*)d_in[2];
  const float* kqv_w_h   = (const float*)d_in[3];
  const float* kqv_bn_h  = (const float*)d_in[4];
  const float* lbn_h     = (const float*)d_in[5];
  const float* rel_h     = (const float*)d_in[6];
  const float* kqv_w_w   = (const float*)d_in[7];
  const float* kqv_bn_w  = (const float*)d_in[8];
  const float* lbn_w     = (const float*)d_in[9];
  const float* rel_w     = (const float*)d_in[10];
  const float* conv3_w   = (const float*)d_in[11];
  const float* bn3       = (const float*)d_in[12];
  float* outp = (float*)d_out;
  char* ws = (char*)d_ws;

  float* A    = (float*)(ws);                    // 8 MiB
  uint4* kvV  = (uint4*)(ws + 8388608);          // 4 MiB
  uint2* kvK  = (uint2*)(ws + 12582912);         // 2 MiB
  float* qb   = (float*)(ws + 14680064);         // 4 MiB (f32 q)
  uint4* rqkH = (uint4*)(ws + 18874368);
  uint4* rveH = (uint4*)(ws + 18882560);
  uint4* rqkW = (uint4*)(ws + 18890752);
  uint4* rveW = (uint4*)(ws + 18894848);

  // conv1 + bn1 + relu (blocks 0..511) and rel_enc packing (blocks 512,513)
  k_conv1<<<514, 256, 0, stream>>>(x, conv1_w, bn1, A,
                                   rel_h, rel_w, rqkH, rveH, rqkW, rveW);

  // axial-H: n = w (128), seq = h (256)
  k_kqv<256,128,1><<<dim3(128,4), 512, 0, stream>>>(A, kqv_w_h, kqv_bn_h, kvV, kvK, qb);
  k_attnH<<<1024, 256, 0, stream>>>(kvV, kvK, qb, rqkH, rveH, lbn_h, A);

  // axial-W: n = h (256), seq = w (128); relu fused
  k_kqv<128,1,128><<<dim3(256,2), 512, 0, stream>>>(A, kqv_w_w, kqv_bn_w, kvV, kvK, qb);
  k_attnW<<<1024, 256, 0, stream>>>(kvV, kvK, qb, rqkW, rveW, lbn_w, A);

  // conv3 + bn3 + residual + relu : A NHWC -> out NCHW
  k_conv3<<<512, 256, 0, stream>>>(A, conv3_w, bn3, x, outp);
}

// Round 13
// 176.930 us; speedup vs baseline: 1.0034x; 1.0034x over previous
//
#include <hip/hip_runtime.h>
#include <stdint.h>

#define EPSF 1e-5f
#define LOG2E 1.4426950408889634f

typedef float f32x2 __attribute__((ext_vector_type(2)));
typedef float f32x4 __attribute__((ext_vector_type(4)));

__device__ __forceinline__ float bflo(uint32_t u){ union{uint32_t u;float f;}c; c.u=u<<16; return c.f; }
__device__ __forceinline__ float bfhi(uint32_t u){ union{uint32_t u;float f;}c; c.u=u&0xffff0000u; return c.f; }
// raw high-half: value == bf16_hi * (1+delta), |delta| <= 2^-7
__device__ __forceinline__ float bfhiraw(uint32_t u){ union{uint32_t u;float f;}c; c.u=u; return c.f; }
__device__ __forceinline__ uint32_t f2bf(float f){ union{float f;uint32_t u;}c; c.f=f; uint32_t u=c.u; return (u + 0x7fffu + ((u>>16)&1u)) >> 16; }
__device__ __forceinline__ uint32_t pk2(float a, float b){ return f2bf(a) | (f2bf(b)<<16); }

// ---- VOP3P packed f32 (gfx950): throughput-neutral vs scalar, kept for issue-slot density ----
__device__ __forceinline__ f32x2 pk_add(f32x2 a, f32x2 b){
  f32x2 d; asm("v_pk_add_f32 %0, %1, %2" : "=v"(d) : "v"(a), "v"(b)); return d;
}
__device__ __forceinline__ f32x2 pk_mul(f32x2 a, f32x2 b){
  f32x2 d; asm("v_pk_mul_f32 %0, %1, %2" : "=v"(d) : "v"(a), "v"(b)); return d;
}
__device__ __forceinline__ f32x2 pk_fma(f32x2 a, f32x2 b, f32x2 c){
  f32x2 d; asm("v_pk_fma_f32 %0, %1, %2, %3" : "=v"(d) : "v"(a), "v"(b), "v"(c)); return d;
}
__device__ __forceinline__ f32x2 up2(uint32_t u){
  f32x2 r; r.x = bflo(u); r.y = bfhiraw(u); return r;
}

// ---------------- conv1 + bn + relu (+ relpack tail blocks, bf16 tables) ----------------
__global__ __launch_bounds__(256)
void k_conv1(const float* __restrict__ in, const float* __restrict__ w,
             const float* __restrict__ bn, float* __restrict__ out,
             const float* __restrict__ relH, const float* __restrict__ relW,
             uint4* __restrict__ rqkH, uint4* __restrict__ rveH,
             uint4* __restrict__ rqkW, uint4* __restrict__ rveW) {
  if (blockIdx.x >= 512) {
    int which = blockIdx.x - 512;
    int NJ = which ? 255 : 511;
    const float* rel = which ? relW : relH;
    uint4* rqk = which ? rqkW : rqkH;
    uint4* rve = which ? rveW : rveH;
    const float* q = rel;
    const float* k = rel + 4*NJ;
    const float* v = rel + 8*NJ;
    for (int j = threadIdx.x; j < NJ; j += 256) {
      int jr = NJ-1-j;
      uint4 a;
      a.x = pk2(q[0*NJ+j], q[1*NJ+j]);
      a.y = pk2(q[2*NJ+j], q[3*NJ+j]);
      a.z = pk2(k[0*NJ+jr], k[1*NJ+jr]);
      a.w = pk2(k[2*NJ+jr], k[3*NJ+jr]);
      rqk[j] = a;
      uint4 b;
      b.x = pk2(v[0*NJ+j], v[1*NJ+j]);
      b.y = pk2(v[2*NJ+j], v[3*NJ+j]);
      b.z = pk2(v[4*NJ+j], v[5*NJ+j]);
      b.w = pk2(v[6*NJ+j], v[7*NJ+j]);
      rve[j] = b;
    }
    return;
  }
  __shared__ float L[64*65];
  int tid = threadIdx.x;
  int p0 = blockIdx.x * 64;
  int lane = tid & 63;
  int wvs = __builtin_amdgcn_readfirstlane(tid >> 6);
  #pragma unroll
  for (int rr = 0; rr < 16; ++rr) {
    int c = wvs*16 + rr;
    L[lane*65 + c] = in[(size_t)c*32768 + p0 + lane];
  }
  __syncthreads();
  f32x2 xv2[32];
  #pragma unroll
  for (int c2 = 0; c2 < 32; ++c2) {
    xv2[c2].x = L[lane*65 + 2*c2];
    xv2[c2].y = L[lane*65 + 2*c2 + 1];
  }
  float val[16];
  #pragma unroll
  for (int r = 0; r < 16; ++r) {
    int o = wvs*16 + r;
    const f32x2* wr = (const f32x2*)(w + o*64);
    f32x2 a2 = {0.f, 0.f};
    #pragma unroll
    for (int c2 = 0; c2 < 32; ++c2) a2 = wr[c2]*xv2[c2] + a2;
    float acc = a2.x + a2.y;
    float s = bn[o] * rsqrtf(bn[192+o] + EPSF);
    val[r] = fmaxf(fmaf(acc, s, fmaf(-bn[128+o], s, bn[64+o])), 0.f);
  }
  __syncthreads();
  #pragma unroll
  for (int r = 0; r < 16; ++r) L[lane*65 + wvs*16 + r] = val[r];
  __syncthreads();
  float4* dst = (float4*)(out + (size_t)p0*64);
  #pragma unroll
  for (int k = 0; k < 4; ++k) {
    int f4 = tid + k*256;
    int f = f4*4; int p = f >> 6, o = f & 63;
    float4 v;
    v.x = L[p*65+o]; v.y = L[p*65+o+1]; v.z = L[p*65+o+2]; v.w = L[p*65+o+3];
    dst[f4] = v;
  }
}

// ---------------- fused axial attention (kqv + attn in one kernel) ----------------
struct E4 { f32x2 qe0, qe1, ke0, ke1; };
struct V4 { f32x2 a, b, c, d; };

__device__ __forceinline__ E4 upQK(uint4 u){
  E4 r; r.qe0 = up2(u.x); r.qe1 = up2(u.y); r.ke0 = up2(u.z); r.ke1 = up2(u.w); return r;
}
__device__ __forceinline__ V4 upVE(uint4 u){
  V4 r; r.a = up2(u.x); r.b = up2(u.y); r.c = up2(u.z); r.d = up2(u.w); return r;
}
// logit2 = kt.(q + ke'') + q.qe'
__device__ __forceinline__ float pairA(f32x2 q01, f32x2 q23, const E4& e,
                                       f32x2 ktlo, f32x2 kthi) {
  f32x2 t0 = pk_add(q01, e.ke0);
  f32x2 t1 = pk_add(q23, e.ke1);
  f32x2 s  = pk_mul(t0, ktlo);
  s = pk_fma(t1, kthi, s);
  s = pk_fma(q01, e.qe0, s);
  s = pk_fma(q23, e.qe1, s);
  return s.x + s.y;
}
__device__ __forceinline__ void pairB(float ex, const V4& ve,
                                      f32x2 va01, f32x2 va23, f32x2 vb01, f32x2 vb23,
                                      f32x2* A, float& ss) {
  ss += ex;
  f32x2 e2; e2.x = ex; e2.y = ex;
  A[0] = pk_fma(e2, pk_add(va01, ve.a), A[0]);
  A[1] = pk_fma(e2, pk_add(va23, ve.b), A[1]);
  A[2] = pk_fma(e2, pk_add(vb01, ve.c), A[2]);
  A[3] = pk_fma(e2, pk_add(vb23, ve.d), A[3]);
}

// Block = (n-block of NB, head). T = NB*(LEN/4)*G = 256 threads.
// Phase 1 (fused kqv): stage 64 input rows/chunk; wave wv computes channels
// o = hd*16 + wv*4 + [0,4) for its lane's row (s_load weights); writes
// K~ (A0L-scaled), Q, V directly into LDS staging (f32, no bf16 round-trip).
// Phase 2: r11 windowed online-softmax core, unchanged.
template<int LEN, int NB, int G, bool RELUO, int XS, int NS, int RS, int CS>
__device__ __forceinline__
void attn_body(const float* __restrict__ in, const float* __restrict__ kw,
               const float* __restrict__ kbn, const uint4* __restrict__ rqk,
               const uint4* __restrict__ rve, const float* __restrict__ lbn,
               float* __restrict__ out) {
  constexpr int NJ = 2*LEN-1;
  constexpr int NJ4 = (NJ+1)/4;
  constexpr int XT = LEN/4;
  constexpr int T = NB*XT*G;
  constexpr int YR = LEN/G;
  static_assert(T == 256, "chunk staging assumes 256 threads");
  constexpr size_t PS = (size_t)NB*LEN*64 + (size_t)NJ4*128 + (size_t)64*65*4;
  int nb = blockIdx.x >> 3;
  int hd = blockIdx.x & 7;
  int n0 = nb * NB;
  int t  = threadIdx.x;

  __shared__ __align__(16) char pool[PS];
  f32x4* sKt = (f32x4*)(pool);                                 // [NB*LEN] A0L*k
  f32x4* sVa = (f32x4*)(pool + (size_t)NB*LEN*16);             // [NB*LEN] v0..3
  f32x4* sVb = (f32x4*)(pool + (size_t)NB*LEN*32);             // [NB*LEN] v4..7
  uint4* tQK = (uint4*)(pool + (size_t)NB*LEN*48);             // [4][NJ4]
  uint4* tVE = (uint4*)(pool + (size_t)NB*LEN*48 + (size_t)NJ4*64); // [4][NJ4]
  f32x4* tQf = (f32x4*)(pool + (size_t)NB*LEN*48 + (size_t)NJ4*128); // [NB*LEN] q f32
  float* Lb  = (float*)(pool + (size_t)NB*LEN*64 + (size_t)NJ4*128); // [64*65]

  float A0L, A1L, A2L;
  {
    int c0 = hd, c1 = 8+hd, c2 = 16+hd;
    A0L = lbn[c0]*rsqrtf(lbn[72+c0]+EPSF)*LOG2E;
    A1L = lbn[c1]*rsqrtf(lbn[72+c1]+EPSF)*LOG2E;
    A2L = lbn[c2]*rsqrtf(lbn[72+c2]+EPSF)*LOG2E;
  }
  float A0g = (fabsf(A0L) > 1e-25f) ? A0L : copysignf(1e-25f, A0L);
  float ratio = A2L / A0g;

  // ---- rel tables (bf16, prescaled) ----
  for (int j = t; j < NJ; j += T) {
    uint4 a = rqk[j];
    uint4 sq;
    sq.x = pk2(bflo(a.x)*A1L,   bfhi(a.x)*A1L);
    sq.y = pk2(bflo(a.y)*A1L,   bfhi(a.y)*A1L);
    sq.z = pk2(bflo(a.z)*ratio, bfhi(a.z)*ratio);
    sq.w = pk2(bflo(a.w)*ratio, bfhi(a.w)*ratio);
    int r = j & 3, mm = j >> 2;
    tQK[r*NJ4 + mm] = sq;
    tVE[r*NJ4 + mm] = rve[j];
  }

  // ---- fused kqv: 4 chunks of 64 rows ----
  int lane = t & 63;
  int wv = __builtin_amdgcn_readfirstlane(t >> 6);
  float sC[4], bC[4];
  #pragma unroll
  for (int r = 0; r < 4; ++r) {
    int o = hd*16 + wv*4 + r;
    float s = kbn[o] * rsqrtf(kbn[384+o] + EPSF);
    sC[r] = s;
    bC[r] = fmaf(-kbn[256+o], s, kbn[128+o]);
  }
  for (int c0 = 0; c0 < NB*LEN; c0 += 64) {
    __syncthreads();   // previous chunk's readers done with Lb
    #pragma unroll
    for (int k = 0; k < 16; ++k) {
      int idx = t + k*256;
      int row = idx >> 6, c = idx & 63;
      int gi = c0 + row;
      int nn = gi / LEN, yy = gi % LEN;
      Lb[row*65 + c] = in[((size_t)yy*RS + (size_t)(n0+nn)*CS)*64 + c];
    }
    __syncthreads();
    f32x2 xv2[32];
    #pragma unroll
    for (int c2 = 0; c2 < 32; ++c2) {
      xv2[c2].x = Lb[lane*65 + 2*c2];
      xv2[c2].y = Lb[lane*65 + 2*c2 + 1];
    }
    float val[4];
    #pragma unroll
    for (int r = 0; r < 4; ++r) {
      int o = hd*16 + wv*4 + r;
      const f32x2* wr = (const f32x2*)(kw + o*64);   // wave-uniform -> s_load
      f32x2 a2 = {0.f, 0.f};
      #pragma unroll
      for (int c2 = 0; c2 < 32; ++c2) a2 = wr[c2]*xv2[c2] + a2;
      val[r] = fmaf(a2.x + a2.y, sC[r], bC[r]);
    }
    int i = c0 + lane;
    f32x4 v4; v4.x = val[0]; v4.y = val[1]; v4.z = val[2]; v4.w = val[3];
    if (wv == 0) {
      f32x4 kt; kt.x = val[0]*A0g; kt.y = val[1]*A0g; kt.z = val[2]*A0g; kt.w = val[3]*A0g;
      sKt[i] = kt;
    } else if (wv == 1) {
      tQf[i] = v4;
    } else if (wv == 2) {
      sVa[i] = v4;
    } else {
      sVb[i] = v4;
    }
  }
  __syncthreads();

  // ---- phase 2: windowed online-softmax core (r11) ----
  int g  = t / (NB*XT);
  int u  = t % (NB*XT);
  int ni = u / XT;
  int tl = u % XT;
  int y0 = g * YR;
  int x0 = 4 * tl;
  int niL = ni * LEN;

  f32x2 q01[4], q23[4];
  #pragma unroll
  for (int i = 0; i < 4; ++i) {
    f32x4 qq = tQf[niL + x0 + i];
    q01[i].x = qq.x; q01[i].y = qq.y;
    q23[i].x = qq.z; q23[i].y = qq.w;
  }

  float m[4], ss[4];
  f32x2 acc[4][4];
  #pragma unroll
  for (int i=0;i<4;++i){ m[i]=-3.0e38f; ss[i]=0.f;
    #pragma unroll
    for(int d=0;d<4;++d){ acc[i][d].x=0.f; acc[i][d].y=0.f; } }

  int mi = ((y0 + LEN-1) >> 2) - (x0 >> 2);
  E4 Wq0 = upQK(tQK[0*NJ4 + mi]), Wq1 = upQK(tQK[1*NJ4 + mi]), Wq2 = upQK(tQK[2*NJ4 + mi]);
  V4 Wv0 = upVE(tVE[0*NJ4 + mi]), Wv1 = upVE(tVE[1*NJ4 + mi]), Wv2 = upVE(tVE[2*NJ4 + mi]);

  for (int cc = 0; cc < YR/4; ++cc) {
    int yb = niL + y0 + 4*cc;
    int ma = mi + cc;
    int mb = ma + 1;
    float lr[4][4];
    // ---- pass A (parities 3,0,1,2) ----
    E4 E3 = upQK(tQK[3*NJ4 + ma]);
    { f32x4 kt = sKt[yb]; f32x2 kl = kt.lo, kh = kt.hi;
      lr[0][0]=pairA(q01[0],q23[0],E3, kl,kh); lr[1][0]=pairA(q01[1],q23[1],Wq2,kl,kh);
      lr[2][0]=pairA(q01[2],q23[2],Wq1,kl,kh); lr[3][0]=pairA(q01[3],q23[3],Wq0,kl,kh); }
    E4 E0 = upQK(tQK[0*NJ4 + mb]);
    { f32x4 kt = sKt[yb+1]; f32x2 kl = kt.lo, kh = kt.hi;
      lr[0][1]=pairA(q01[0],q23[0],E0, kl,kh); lr[1][1]=pairA(q01[1],q23[1],E3, kl,kh);
      lr[2][1]=pairA(q01[2],q23[2],Wq2,kl,kh); lr[3][1]=pairA(q01[3],q23[3],Wq1,kl,kh); }
    E4 E1 = upQK(tQK[1*NJ4 + mb]);
    { f32x4 kt = sKt[yb+2]; f32x2 kl = kt.lo, kh = kt.hi;
      lr[0][2]=pairA(q01[0],q23[0],E1, kl,kh); lr[1][2]=pairA(q01[1],q23[1],E0, kl,kh);
      lr[2][2]=pairA(q01[2],q23[2],E3, kl,kh); lr[3][2]=pairA(q01[3],q23[3],Wq2,kl,kh); }
    E4 E2 = upQK(tQK[2*NJ4 + mb]);
    { f32x4 kt = sKt[yb+3]; f32x2 kl = kt.lo, kh = kt.hi;
      lr[0][3]=pairA(q01[0],q23[0],E2, kl,kh); lr[1][3]=pairA(q01[1],q23[1],E1, kl,kh);
      lr[2][3]=pairA(q01[2],q23[2],E0, kl,kh); lr[3][3]=pairA(q01[3],q23[3],E3, kl,kh); }
    Wq0 = E0; Wq1 = E1; Wq2 = E2;
    // ---- chunk rescale, skipped when no lane's max grew (exact) ----
    float cm[4];
    bool need = false;
    #pragma unroll
    for (int i = 0; i < 4; ++i) {
      cm[i] = fmaxf(fmaxf(lr[i][0], lr[i][1]), fmaxf(lr[i][2], lr[i][3]));
      need = need || (cm[i] > m[i]);
    }
    if (__any(need)) {
      #pragma unroll
      for (int i = 0; i < 4; ++i) {
        float mn = fmaxf(m[i], cm[i]);
        float sc = __builtin_amdgcn_exp2f(m[i] - mn);
        m[i] = mn; ss[i] *= sc;
        f32x2 sc2; sc2.x = sc; sc2.y = sc;
        #pragma unroll
        for (int d = 0; d < 4; ++d) acc[i][d] = pk_mul(acc[i][d], sc2);
      }
    }
    // ---- pass B (same window schedule) ----
    V4 F3 = upVE(tVE[3*NJ4 + ma]);
    { f32x4 va = sVa[yb], vb = sVb[yb];
      pairB(__builtin_amdgcn_exp2f(lr[0][0]-m[0]), F3,  va.lo,va.hi,vb.lo,vb.hi, acc[0], ss[0]);
      pairB(__builtin_amdgcn_exp2f(lr[1][0]-m[1]), Wv2, va.lo,va.hi,vb.lo,vb.hi, acc[1], ss[1]);
      pairB(__builtin_amdgcn_exp2f(lr[2][0]-m[2]), Wv1, va.lo,va.hi,vb.lo,vb.hi, acc[2], ss[2]);
      pairB(__builtin_amdgcn_exp2f(lr[3][0]-m[3]), Wv0, va.lo,va.hi,vb.lo,vb.hi, acc[3], ss[3]); }
    V4 F0 = upVE(tVE[0*NJ4 + mb]);
    { f32x4 va = sVa[yb+1], vb = sVb[yb+1];
      pairB(__builtin_amdgcn_exp2f(lr[0][1]-m[0]), F0,  va.lo,va.hi,vb.lo,vb.hi, acc[0], ss[0]);
      pairB(__builtin_amdgcn_exp2f(lr[1][1]-m[1]), F3,  va.lo,va.hi,vb.lo,vb.hi, acc[1], ss[1]);
      pairB(__builtin_amdgcn_exp2f(lr[2][1]-m[2]), Wv2, va.lo,va.hi,vb.lo,vb.hi, acc[2], ss[2]);
      pairB(__builtin_amdgcn_exp2f(lr[3][1]-m[3]), Wv1, va.lo,va.hi,vb.lo,vb.hi, acc[3], ss[3]); }
    V4 F1 = upVE(tVE[1*NJ4 + mb]);
    { f32x4 va = sVa[yb+2], vb = sVb[yb+2];
      pairB(__builtin_amdgcn_exp2f(lr[0][2]-m[0]), F1,  va.lo,va.hi,vb.lo,vb.hi, acc[0], ss[0]);
      pairB(__builtin_amdgcn_exp2f(lr[1][2]-m[1]), F0,  va.lo,va.hi,vb.lo,vb.hi, acc[1], ss[1]);
      pairB(__builtin_amdgcn_exp2f(lr[2][2]-m[2]), F3,  va.lo,va.hi,vb.lo,vb.hi, acc[2], ss[2]);
      pairB(__builtin_amdgcn_exp2f(lr[3][2]-m[3]), Wv2, va.lo,va.hi,vb.lo,vb.hi, acc[3], ss[3]); }
    V4 F2 = upVE(tVE[2*NJ4 + mb]);
    { f32x4 va = sVa[yb+3], vb = sVb[yb+3];
      pairB(__builtin_amdgcn_exp2f(lr[0][3]-m[0]), F2,  va.lo,va.hi,vb.lo,vb.hi, acc[0], ss[0]);
      pairB(__builtin_amdgcn_exp2f(lr[1][3]-m[1]), F1,  va.lo,va.hi,vb.lo,vb.hi, acc[1], ss[1]);
      pairB(__builtin_amdgcn_exp2f(lr[2][3]-m[2]), F0,  va.lo,va.hi,vb.lo,vb.hi, acc[2], ss[2]);
      pairB(__builtin_amdgcn_exp2f(lr[3][3]-m[3]), F3,  va.lo,va.hi,vb.lo,vb.hi, acc[3], ss[3]); }
    Wv0 = F0; Wv1 = F1; Wv2 = F2;
  }

  // ---- one-shot G-way merge via LDS (reuses staging region; all dead) ----
  __syncthreads();
  float4* M0 = (float4*)(pool);
  float4* M1 = (float4*)(pool + (size_t)(G-1)*NB*LEN*16);
  float2* MS = (float2*)(pool + (size_t)(G-1)*NB*LEN*32);
  int xb = niL + x0;
  if (g > 0) {
    #pragma unroll
    for (int i = 0; i < 4; ++i) {
      int slot = (g-1)*NB*LEN + xb + i;
      M0[slot] = make_float4(acc[i][0].x,acc[i][0].y,acc[i][1].x,acc[i][1].y);
      M1[slot] = make_float4(acc[i][2].x,acc[i][2].y,acc[i][3].x,acc[i][3].y);
      MS[slot] = make_float2(m[i], ss[i]);
    }
  }
  __syncthreads();
  if (g == 0) {
    #pragma unroll
    for (int i = 0; i < 4; ++i) {
      float M = m[i];
      float2 oms[G-1];
      #pragma unroll
      for (int gg = 1; gg < G; ++gg) {
        oms[gg-1] = MS[(gg-1)*NB*LEN + xb + i];
        M = fmaxf(M, oms[gg-1].x);
      }
      float w0 = __builtin_amdgcn_exp2f(m[i] - M);
      float st = ss[i]*w0;
      float a[8];
      a[0]=acc[i][0].x*w0; a[1]=acc[i][0].y*w0; a[2]=acc[i][1].x*w0; a[3]=acc[i][1].y*w0;
      a[4]=acc[i][2].x*w0; a[5]=acc[i][2].y*w0; a[6]=acc[i][3].x*w0; a[7]=acc[i][3].y*w0;
      #pragma unroll
      for (int gg = 1; gg < G; ++gg) {
        int slot = (gg-1)*NB*LEN + xb + i;
        float wg = __builtin_amdgcn_exp2f(oms[gg-1].x - M);
        st += oms[gg-1].y*wg;
        float4 a0 = M0[slot];
        float4 a1 = M1[slot];
        a[0] = fmaf(a0.x, wg, a[0]); a[1] = fmaf(a0.y, wg, a[1]);
        a[2] = fmaf(a0.z, wg, a[2]); a[3] = fmaf(a0.w, wg, a[3]);
        a[4] = fmaf(a1.x, wg, a[4]); a[5] = fmaf(a1.y, wg, a[5]);
        a[6] = fmaf(a1.z, wg, a[6]); a[7] = fmaf(a1.w, wg, a[7]);
      }
      float inv = 1.0f / st;
      float* dst = out + ((size_t)(x0+i)*XS + (size_t)(n0+ni)*NS)*64 + hd*8;
      float4 lo, hi;
      lo.x = a[0]*inv; lo.y = a[1]*inv; lo.z = a[2]*inv; lo.w = a[3]*inv;
      hi.x = a[4]*inv; hi.y = a[5]*inv; hi.z = a[6]*inv; hi.w = a[7]*inv;
      if (RELUO) {
        lo.x=fmaxf(lo.x,0.f); lo.y=fmaxf(lo.y,0.f); lo.z=fmaxf(lo.z,0.f); lo.w=fmaxf(lo.w,0.f);
        hi.x=fmaxf(hi.x,0.f); hi.y=fmaxf(hi.y,0.f); hi.z=fmaxf(hi.z,0.f); hi.w=fmaxf(hi.w,0.f);
      }
      *(float4*)dst = lo;
      *((float4*)dst + 1) = hi;
    }
  }
}

// Distinct names so rocprof attributes H vs W separately.
__global__ __launch_bounds__(256, 2)
void k_attnH(const float* __restrict__ in, const float* __restrict__ kw,
             const float* __restrict__ kbn, const uint4* __restrict__ rqk,
             const uint4* __restrict__ rve, const float* __restrict__ lbn,
             float* __restrict__ out) {
  attn_body<256,1,4,false,128,1,128,1>(in, kw, kbn, rqk, rve, lbn, out);
}
__global__ __launch_bounds__(256, 2)
void k_attnW(const float* __restrict__ in, const float* __restrict__ kw,
             const float* __restrict__ kbn, const uint4* __restrict__ rqk,
             const uint4* __restrict__ rve, const float* __restrict__ lbn,
             float* __restrict__ out) {
  attn_body<128,2,4,true,1,128,1,128>(in, kw, kbn, rqk, rve, lbn, out);
}

// ---------------- conv3 + bn + residual + relu : NHWC in -> NCHW out ----------------
__global__ __launch_bounds__(256)
void k_conv3(const float* __restrict__ in, const float* __restrict__ w,
             const float* __restrict__ bn, const float* __restrict__ resid,
             float* __restrict__ out) {
  __shared__ float L[64*65];
  int tid = threadIdx.x;
  int p0 = blockIdx.x * 64;
  const float4* src = (const float4*)(in + (size_t)p0*64);
  #pragma unroll
  for (int k = 0; k < 4; ++k) {
    int f4 = tid + k*256;
    float4 v = src[f4];
    int f = f4*4; int p = f >> 6, o = f & 63;
    L[p*65+o] = v.x; L[p*65+o+1] = v.y; L[p*65+o+2] = v.z; L[p*65+o+3] = v.w;
  }
  __syncthreads();
  int lane = tid & 63;
  int wvs = __builtin_amdgcn_readfirstlane(tid >> 6);
  f32x2 xv2[32];
  #pragma unroll
  for (int c2 = 0; c2 < 32; ++c2) {
    xv2[c2].x = L[lane*65 + 2*c2];
    xv2[c2].y = L[lane*65 + 2*c2 + 1];
  }
  #pragma unroll
  for (int r = 0; r < 16; ++r) {
    int o = wvs*16 + r;
    const f32x2* wr = (const f32x2*)(w + o*64);
    f32x2 a2 = {0.f, 0.f};
    #pragma unroll
    for (int c2 = 0; c2 < 32; ++c2) a2 = wr[c2]*xv2[c2] + a2;
    float acc = a2.x + a2.y;
    float s = bn[o] * rsqrtf(bn[192+o] + EPSF);
    float val = fmaf(acc, s, fmaf(-bn[128+o], s, bn[64+o]));
    size_t idx = (size_t)o*32768 + p0 + lane;
    out[idx] = fmaxf(val + resid[idx], 0.f);
  }
}

extern "C" void kernel_launch(void* const* d_in, const int* in_sizes, int n_in,
                              void* d_out, int out_size, void* d_ws, size_t ws_size,
                              hipStream_t stream) {
  const float* x         = (const float*)d_in[0];
  const float* conv1_w   = (const float*)d_in[1];
  const float* bn1       = (const float*)d_in[2];
  const float* kqv_w_h   = (const float*)d_in[3];
  const float* kqv_bn_h  = (const float*)d_in[4];
  const float* lbn_h     = (const float*)d_in[5];
  const float* rel_h     = (const float*)d_in[6];
  const float* kqv_w_w   = (const float*)d_in[7];
  const float* kqv_bn_w  = (const float*)d_in[8];
  const float* lbn_w     = (const float*)d_in[9];
  const float* rel_w     = (const float*)d_in[10];
  const float* conv3_w   = (const float*)d_in[11];
  const float* bn3       = (const float*)d_in[12];
  float* outp = (float*)d_out;
  char* ws = (char*)d_ws;

  float* A    = (float*)(ws);                    // 8 MiB: conv1 out, then attnW out
  float* B    = (float*)(ws + 8388608);          // 8 MiB: attnH out
  uint4* rqkH = (uint4*)(ws + 16777216);
  uint4* rveH = (uint4*)(ws + 16785408);
  uint4* rqkW = (uint4*)(ws + 16793600);
  uint4* rveW = (uint4*)(ws + 16797696);

  // conv1 + bn1 + relu (blocks 0..511) and rel_enc packing (blocks 512,513)
  k_conv1<<<514, 256, 0, stream>>>(x, conv1_w, bn1, A,
                                   rel_h, rel_w, rqkH, rveH, rqkW, rveW);

  // axial-H (fused kqv+attn): A -> B
  k_attnH<<<1024, 256, 0, stream>>>(A, kqv_w_h, kqv_bn_h, rqkH, rveH, lbn_h, B);

  // axial-W (fused kqv+attn, relu): B -> A
  k_attnW<<<1024, 256, 0, stream>>>(B, kqv_w_w, kqv_bn_w, rqkW, rveW, lbn_w, A);

  // conv3 + bn3 + residual + relu : A NHWC -> out NCHW
  k_conv3<<<512, 256, 0, stream>>>(A, conv3_w, bn3, x, outp);
}

// Round 14
// 171.381 us; speedup vs baseline: 1.0359x; 1.0324x over previous
//
#include <hip/hip_runtime.h>
#include <stdint.h>

#define EPSF 1e-5f
#define LOG2E 1.4426950408889634f

typedef float f32x2 __attribute__((ext_vector_type(2)));
typedef float f32x4 __attribute__((ext_vector_type(4)));

__device__ __forceinline__ float bflo(uint32_t u){ union{uint32_t u;float f;}c; c.u=u<<16; return c.f; }
__device__ __forceinline__ float bfhi(uint32_t u){ union{uint32_t u;float f;}c; c.u=u&0xffff0000u; return c.f; }
// raw high-half: value == bf16_hi * (1+delta), |delta| <= 2^-7
__device__ __forceinline__ float bfhiraw(uint32_t u){ union{uint32_t u;float f;}c; c.u=u; return c.f; }
__device__ __forceinline__ uint32_t f2bf(float f){ union{float f;uint32_t u;}c; c.f=f; uint32_t u=c.u; return (u + 0x7fffu + ((u>>16)&1u)) >> 16; }
__device__ __forceinline__ uint32_t pk2(float a, float b){ return f2bf(a) | (f2bf(b)<<16); }

// ---- VOP3P packed f32 (gfx950): throughput-neutral vs scalar, kept for issue-slot density ----
__device__ __forceinline__ f32x2 pk_add(f32x2 a, f32x2 b){
  f32x2 d; asm("v_pk_add_f32 %0, %1, %2" : "=v"(d) : "v"(a), "v"(b)); return d;
}
__device__ __forceinline__ f32x2 pk_mul(f32x2 a, f32x2 b){
  f32x2 d; asm("v_pk_mul_f32 %0, %1, %2" : "=v"(d) : "v"(a), "v"(b)); return d;
}
__device__ __forceinline__ f32x2 pk_fma(f32x2 a, f32x2 b, f32x2 c){
  f32x2 d; asm("v_pk_fma_f32 %0, %1, %2, %3" : "=v"(d) : "v"(a), "v"(b), "v"(c)); return d;
}
__device__ __forceinline__ f32x2 up2(uint32_t u){
  f32x2 r; r.x = bflo(u); r.y = bfhiraw(u); return r;
}

// ---------------- conv1 + bn + relu (+ relpack tail blocks) ----------------
// blocks [0,512): conv1 NCHW -> NHWC. blocks 512/513: rel_enc packing (H/W).
__global__ __launch_bounds__(256)
void k_conv1(const float* __restrict__ in, const float* __restrict__ w,
             const float* __restrict__ bn, float* __restrict__ out,
             const float* __restrict__ relH, const float* __restrict__ relW,
             uint4* __restrict__ rqkH, uint4* __restrict__ rveH,
             uint4* __restrict__ rqkW, uint4* __restrict__ rveW) {
  if (blockIdx.x >= 512) {
    int which = blockIdx.x - 512;
    int NJ = which ? 255 : 511;
    const float* rel = which ? relW : relH;
    uint4* rqk = which ? rqkW : rqkH;
    uint4* rve = which ? rveW : rveH;
    const float* q = rel;
    const float* k = rel + 4*NJ;
    const float* v = rel + 8*NJ;
    for (int j = threadIdx.x; j < NJ; j += 256) {
      int jr = NJ-1-j;
      uint4 a;
      a.x = pk2(q[0*NJ+j], q[1*NJ+j]);
      a.y = pk2(q[2*NJ+j], q[3*NJ+j]);
      a.z = pk2(k[0*NJ+jr], k[1*NJ+jr]);
      a.w = pk2(k[2*NJ+jr], k[3*NJ+jr]);
      rqk[j] = a;
      uint4 b;
      b.x = pk2(v[0*NJ+j], v[1*NJ+j]);
      b.y = pk2(v[2*NJ+j], v[3*NJ+j]);
      b.z = pk2(v[4*NJ+j], v[5*NJ+j]);
      b.w = pk2(v[6*NJ+j], v[7*NJ+j]);
      rve[j] = b;
    }
    return;
  }
  __shared__ float L[64*65];
  int tid = threadIdx.x;
  int p0 = blockIdx.x * 64;
  int lane = tid & 63;
  int wvs = __builtin_amdgcn_readfirstlane(tid >> 6);
  #pragma unroll
  for (int rr = 0; rr < 16; ++rr) {
    int c = wvs*16 + rr;
    L[lane*65 + c] = in[(size_t)c*32768 + p0 + lane];
  }
  __syncthreads();
  f32x2 xv2[32];
  #pragma unroll
  for (int c2 = 0; c2 < 32; ++c2) {
    xv2[c2].x = L[lane*65 + 2*c2];
    xv2[c2].y = L[lane*65 + 2*c2 + 1];
  }
  float val[16];
  #pragma unroll
  for (int r = 0; r < 16; ++r) {
    int o = wvs*16 + r;
    const f32x2* wr = (const f32x2*)(w + o*64);
    f32x2 a2 = {0.f, 0.f};
    #pragma unroll
    for (int c2 = 0; c2 < 32; ++c2) a2 = wr[c2]*xv2[c2] + a2;
    float acc = a2.x + a2.y;
    float s = bn[o] * rsqrtf(bn[192+o] + EPSF);
    val[r] = fmaxf(fmaf(acc, s, fmaf(-bn[128+o], s, bn[64+o])), 0.f);
  }
  __syncthreads();
  #pragma unroll
  for (int r = 0; r < 16; ++r) L[lane*65 + wvs*16 + r] = val[r];
  __syncthreads();
  float4* dst = (float4*)(out + (size_t)p0*64);
  #pragma unroll
  for (int k = 0; k < 4; ++k) {
    int f4 = tid + k*256;
    int f = f4*4; int p = f >> 6, o = f & 63;
    float4 v;
    v.x = L[p*65+o]; v.y = L[p*65+o+1]; v.z = L[p*65+o+2]; v.w = L[p*65+o+3];
    dst[f4] = v;
  }
}

// ---------------- kqv projection + bn -> bf16 K/V + f32 Q ----------------
template<int LEN, int RS, int CS>
__global__ __launch_bounds__(512)
void k_kqv(const float* __restrict__ in, const float* __restrict__ w,
           const float* __restrict__ bn, uint4* __restrict__ kvV,
           uint2* __restrict__ kvK, float* __restrict__ qb) {
  __shared__ float L[64*65];
  int tid = threadIdx.x;
  int n = blockIdx.x;
  int y0 = blockIdx.y * 64;
  #pragma unroll
  for (int rr = 0; rr < 8; ++rr) {
    int idx = tid + rr*512;
    int yy = idx >> 6, c = idx & 63;
    L[yy*65 + c] = in[((size_t)(y0+yy)*RS + (size_t)n*CS)*64 + c];
  }
  __syncthreads();
  int hd = __builtin_amdgcn_readfirstlane(tid >> 6);
  int yy = tid & 63;
  f32x2 xv2[32];
  #pragma unroll
  for (int c2 = 0; c2 < 32; ++c2) {
    xv2[c2].x = L[yy*65 + 2*c2];
    xv2[c2].y = L[yy*65 + 2*c2 + 1];
  }
  float val[16];
  #pragma unroll
  for (int r = 0; r < 16; ++r) {
    int o = hd*16 + r;
    const f32x2* wr = (const f32x2*)(w + o*64);
    f32x2 a2 = {0.f, 0.f};
    #pragma unroll
    for (int c2 = 0; c2 < 32; ++c2) a2 = wr[c2]*xv2[c2] + a2;
    float acc = a2.x + a2.y;
    float s = bn[o] * rsqrtf(bn[384+o] + EPSF);
    val[r] = fmaf(acc, s, fmaf(-bn[256+o], s, bn[128+o]));
  }
  size_t base = ((size_t)n*8 + hd)*LEN + (y0 + yy);
  kvK[base] = make_uint2(pk2(val[0],val[1]), pk2(val[2],val[3]));
  kvV[base] = make_uint4(pk2(val[8],val[9]),  pk2(val[10],val[11]),
                         pk2(val[12],val[13]), pk2(val[14],val[15]));
  float4 qq; qq.x = val[4]; qq.y = val[5]; qq.z = val[6]; qq.w = val[7];
  *(float4*)(qb + base*4) = qq;
}

// ---------------- axial attention core (shared device body) ----------------
struct E4 { f32x2 qe0, qe1, ke0, ke1; };   // unpacked qe'/ke'' entry
struct V4 { f32x2 a, b, c, d; };           // unpacked ve entry

__device__ __forceinline__ E4 upQK(uint4 u){
  E4 r; r.qe0 = up2(u.x); r.qe1 = up2(u.y); r.ke0 = up2(u.z); r.ke1 = up2(u.w); return r;
}
__device__ __forceinline__ V4 upVE(uint4 u){
  V4 r; r.a = up2(u.x); r.b = up2(u.y); r.c = up2(u.z); r.d = up2(u.w); return r;
}
// logit2 = kt.(q + ke'') + q.qe'
__device__ __forceinline__ float pairA(f32x2 q01, f32x2 q23, const E4& e,
                                       f32x2 ktlo, f32x2 kthi) {
  f32x2 t0 = pk_add(q01, e.ke0);
  f32x2 t1 = pk_add(q23, e.ke1);
  f32x2 s  = pk_mul(t0, ktlo);
  s = pk_fma(t1, kthi, s);
  s = pk_fma(q01, e.qe0, s);
  s = pk_fma(q23, e.qe1, s);
  return s.x + s.y;
}
__device__ __forceinline__ void pairB(float ex, const V4& ve,
                                      f32x2 va01, f32x2 va23, f32x2 vb01, f32x2 vb23,
                                      f32x2* A, float& ss) {
  ss += ex;
  f32x2 e2; e2.x = ex; e2.y = ex;
  A[0] = pk_fma(e2, pk_add(va01, ve.a), A[0]);
  A[1] = pk_fma(e2, pk_add(va23, ve.b), A[1]);
  A[2] = pk_fma(e2, pk_add(vb01, ve.c), A[2]);
  A[3] = pk_fma(e2, pk_add(vb23, ve.d), A[3]);
}

// Block = (n-block of NB, head). T = NB*(LEN/4)*G threads.
template<int LEN, int NB, int G, bool RELUO, int XS, int NS>
__device__ __forceinline__
void attn_body(const uint4* __restrict__ kvV, const uint2* __restrict__ kvK,
               const float* __restrict__ qb, const uint4* __restrict__ rqk,
               const uint4* __restrict__ rve, const float* __restrict__ lbn,
               float* __restrict__ out) {
  constexpr int NJ = 2*LEN-1;
  constexpr int NJ4 = (NJ+1)/4;
  constexpr int XT = LEN/4;
  constexpr int T = NB*XT*G;
  constexpr int YR = LEN/G;
  constexpr size_t S1 = (size_t)NB*LEN*48 + (size_t)NJ4*4*16*2;
  constexpr size_t S2 = (size_t)(G-1)*NB*LEN*40;
  constexpr size_t PS = S1 > S2 ? S1 : S2;
  int nb = blockIdx.x >> 3;
  int hd = blockIdx.x & 7;
  int n0 = nb * NB;
  int t  = threadIdx.x;

  __shared__ __align__(16) char pool[PS];
  f32x4* sKt = (f32x4*)(pool);                                // [NB*LEN] A0L*k
  f32x4* sVa = (f32x4*)(pool + (size_t)NB*LEN*16);            // [NB*LEN] v0..3
  f32x4* sVb = (f32x4*)(pool + (size_t)NB*LEN*32);            // [NB*LEN] v4..7
  uint4* tQK = (uint4*)(pool + (size_t)NB*LEN*48);            // [4][NJ4]
  uint4* tVE = (uint4*)(pool + (size_t)NB*LEN*48 + (size_t)NJ4*64); // [4][NJ4]

  float A0L, A1L, A2L;
  {
    int c0 = hd, c1 = 8+hd, c2 = 16+hd;
    A0L = lbn[c0]*rsqrtf(lbn[72+c0]+EPSF)*LOG2E;
    A1L = lbn[c1]*rsqrtf(lbn[72+c1]+EPSF)*LOG2E;
    A2L = lbn[c2]*rsqrtf(lbn[72+c2]+EPSF)*LOG2E;
  }
  float A0g = (fabsf(A0L) > 1e-25f) ? A0L : copysignf(1e-25f, A0L);
  float ratio = A2L / A0g;

  for (int i = t; i < NB*LEN; i += T) {
    int nn = i / LEN, yy = i % LEN;
    size_t src = ((size_t)(n0+nn)*8 + hd)*LEN + yy;
    uint2 kk = kvK[src];
    uint4 vv = kvV[src];
    f32x4 kt; kt.x=bflo(kk.x)*A0g; kt.y=bfhi(kk.x)*A0g; kt.z=bflo(kk.y)*A0g; kt.w=bfhi(kk.y)*A0g;
    sKt[i] = kt;
    f32x4 va; va.x=bflo(vv.x); va.y=bfhi(vv.x); va.z=bflo(vv.y); va.w=bfhi(vv.y);
    sVa[i] = va;
    f32x4 vb; vb.x=bflo(vv.z); vb.y=bfhi(vv.z); vb.z=bflo(vv.w); vb.w=bfhi(vv.w);
    sVb[i] = vb;
  }
  for (int j = t; j < NJ; j += T) {
    uint4 a = rqk[j];
    uint4 sq;
    sq.x = pk2(bflo(a.x)*A1L,   bfhi(a.x)*A1L);
    sq.y = pk2(bflo(a.y)*A1L,   bfhi(a.y)*A1L);
    sq.z = pk2(bflo(a.z)*ratio, bfhi(a.z)*ratio);
    sq.w = pk2(bflo(a.w)*ratio, bfhi(a.w)*ratio);
    int r = j & 3, mm = j >> 2;
    tQK[r*NJ4 + mm] = sq;
    tVE[r*NJ4 + mm] = rve[j];
  }

  int g  = t / (NB*XT);
  int u  = t % (NB*XT);
  int ni = u / XT;
  int tl = u % XT;
  int y0 = g * YR;
  int x0 = 4 * tl;
  int niL = ni * LEN;
  size_t kb = ((size_t)(n0+ni)*8 + hd)*LEN;

  f32x2 q01[4], q23[4];
  #pragma unroll
  for (int i = 0; i < 4; ++i) {
    f32x4 qq = *(const f32x4*)(qb + (kb + x0 + i)*4);
    q01[i].x = qq.x; q01[i].y = qq.y;
    q23[i].x = qq.z; q23[i].y = qq.w;
  }

  float m[4], ss[4];
  f32x2 acc[4][4];
  #pragma unroll
  for (int i=0;i<4;++i){ m[i]=-3.0e38f; ss[i]=0.f;
    #pragma unroll
    for(int d=0;d<4;++d){ acc[i][d].x=0.f; acc[i][d].y=0.f; } }

  __syncthreads();

  // window prologue: (y0 + LEN-1) & 3 == 3 always (y0, x0 mult of 4)
  int mi = ((y0 + LEN-1) >> 2) - (x0 >> 2);
  E4 Wq0 = upQK(tQK[0*NJ4 + mi]), Wq1 = upQK(tQK[1*NJ4 + mi]), Wq2 = upQK(tQK[2*NJ4 + mi]);
  V4 Wv0 = upVE(tVE[0*NJ4 + mi]), Wv1 = upVE(tVE[1*NJ4 + mi]), Wv2 = upVE(tVE[2*NJ4 + mi]);

  for (int cc = 0; cc < YR/4; ++cc) {
    int yb = niL + y0 + 4*cc;
    int ma = mi + cc;
    int mb = ma + 1;
    float lr[4][4];
    // ---- pass A (parities 3,0,1,2) ----
    E4 E3 = upQK(tQK[3*NJ4 + ma]);
    { f32x4 kt = sKt[yb]; f32x2 kl = kt.lo, kh = kt.hi;
      lr[0][0]=pairA(q01[0],q23[0],E3, kl,kh); lr[1][0]=pairA(q01[1],q23[1],Wq2,kl,kh);
      lr[2][0]=pairA(q01[2],q23[2],Wq1,kl,kh); lr[3][0]=pairA(q01[3],q23[3],Wq0,kl,kh); }
    E4 E0 = upQK(tQK[0*NJ4 + mb]);
    { f32x4 kt = sKt[yb+1]; f32x2 kl = kt.lo, kh = kt.hi;
      lr[0][1]=pairA(q01[0],q23[0],E0, kl,kh); lr[1][1]=pairA(q01[1],q23[1],E3, kl,kh);
      lr[2][1]=pairA(q01[2],q23[2],Wq2,kl,kh); lr[3][1]=pairA(q01[3],q23[3],Wq1,kl,kh); }
    E4 E1 = upQK(tQK[1*NJ4 + mb]);
    { f32x4 kt = sKt[yb+2]; f32x2 kl = kt.lo, kh = kt.hi;
      lr[0][2]=pairA(q01[0],q23[0],E1, kl,kh); lr[1][2]=pairA(q01[1],q23[1],E0, kl,kh);
      lr[2][2]=pairA(q01[2],q23[2],E3, kl,kh); lr[3][2]=pairA(q01[3],q23[3],Wq2,kl,kh); }
    E4 E2 = upQK(tQK[2*NJ4 + mb]);
    { f32x4 kt = sKt[yb+3]; f32x2 kl = kt.lo, kh = kt.hi;
      lr[0][3]=pairA(q01[0],q23[0],E2, kl,kh); lr[1][3]=pairA(q01[1],q23[1],E1, kl,kh);
      lr[2][3]=pairA(q01[2],q23[2],E0, kl,kh); lr[3][3]=pairA(q01[3],q23[3],E3, kl,kh); }
    Wq0 = E0; Wq1 = E1; Wq2 = E2;
    // ---- chunk rescale, skipped when no lane's max grew (exact: skipped == *1.0) ----
    float cm[4];
    bool need = false;
    #pragma unroll
    for (int i = 0; i < 4; ++i) {
      cm[i] = fmaxf(fmaxf(lr[i][0], lr[i][1]), fmaxf(lr[i][2], lr[i][3]));
      need = need || (cm[i] > m[i]);
    }
    if (__any(need)) {
      #pragma unroll
      for (int i = 0; i < 4; ++i) {
        float mn = fmaxf(m[i], cm[i]);
        float sc = __builtin_amdgcn_exp2f(m[i] - mn);
        m[i] = mn; ss[i] *= sc;
        f32x2 sc2; sc2.x = sc; sc2.y = sc;
        #pragma unroll
        for (int d = 0; d < 4; ++d) acc[i][d] = pk_mul(acc[i][d], sc2);
      }
    }
    // ---- pass B (same window schedule) ----
    V4 F3 = upVE(tVE[3*NJ4 + ma]);
    { f32x4 va = sVa[yb], vb = sVb[yb];
      pairB(__builtin_amdgcn_exp2f(lr[0][0]-m[0]), F3,  va.lo,va.hi,vb.lo,vb.hi, acc[0], ss[0]);
      pairB(__builtin_amdgcn_exp2f(lr[1][0]-m[1]), Wv2, va.lo,va.hi,vb.lo,vb.hi, acc[1], ss[1]);
      pairB(__builtin_amdgcn_exp2f(lr[2][0]-m[2]), Wv1, va.lo,va.hi,vb.lo,vb.hi, acc[2], ss[2]);
      pairB(__builtin_amdgcn_exp2f(lr[3][0]-m[3]), Wv0, va.lo,va.hi,vb.lo,vb.hi, acc[3], ss[3]); }
    V4 F0 = upVE(tVE[0*NJ4 + mb]);
    { f32x4 va = sVa[yb+1], vb = sVb[yb+1];
      pairB(__builtin_amdgcn_exp2f(lr[0][1]-m[0]), F0,  va.lo,va.hi,vb.lo,vb.hi, acc[0], ss[0]);
      pairB(__builtin_amdgcn_exp2f(lr[1][1]-m[1]), F3,  va.lo,va.hi,vb.lo,vb.hi, acc[1], ss[1]);
      pairB(__builtin_amdgcn_exp2f(lr[2][1]-m[2]), Wv2, va.lo,va.hi,vb.lo,vb.hi, acc[2], ss[2]);
      pairB(__builtin_amdgcn_exp2f(lr[3][1]-m[3]), Wv1, va.lo,va.hi,vb.lo,vb.hi, acc[3], ss[3]); }
    V4 F1 = upVE(tVE[1*NJ4 + mb]);
    { f32x4 va = sVa[yb+2], vb = sVb[yb+2];
      pairB(__builtin_amdgcn_exp2f(lr[0][2]-m[0]), F1,  va.lo,va.hi,vb.lo,vb.hi, acc[0], ss[0]);
      pairB(__builtin_amdgcn_exp2f(lr[1][2]-m[1]), F0,  va.lo,va.hi,vb.lo,vb.hi, acc[1], ss[1]);
      pairB(__builtin_amdgcn_exp2f(lr[2][2]-m[2]), F3,  va.lo,va.hi,vb.lo,vb.hi, acc[2], ss[2]);
      pairB(__builtin_amdgcn_exp2f(lr[3][2]-m[3]), Wv2, va.lo,va.hi,vb.lo,vb.hi, acc[3], ss[3]); }
    V4 F2 = upVE(tVE[2*NJ4 + mb]);
    { f32x4 va = sVa[yb+3], vb = sVb[yb+3];
      pairB(__builtin_amdgcn_exp2f(lr[0][3]-m[0]), F2,  va.lo,va.hi,vb.lo,vb.hi, acc[0], ss[0]);
      pairB(__builtin_amdgcn_exp2f(lr[1][3]-m[1]), F1,  va.lo,va.hi,vb.lo,vb.hi, acc[1], ss[1]);
      pairB(__builtin_amdgcn_exp2f(lr[2][3]-m[2]), F0,  va.lo,va.hi,vb.lo,vb.hi, acc[2], ss[2]);
      pairB(__builtin_amdgcn_exp2f(lr[3][3]-m[3]), F3,  va.lo,va.hi,vb.lo,vb.hi, acc[3], ss[3]); }
    Wv0 = F0; Wv1 = F1; Wv2 = F2;
  }

  // ---- one-shot G-way merge via LDS ----
  __syncthreads();
  float4* M0 = (float4*)(pool);
  float4* M1 = (float4*)(pool + (size_t)(G-1)*NB*LEN*16);
  float2* MS = (float2*)(pool + (size_t)(G-1)*NB*LEN*32);
  int xb = niL + x0;
  if (g > 0) {
    #pragma unroll
    for (int i = 0; i < 4; ++i) {
      int slot = (g-1)*NB*LEN + xb + i;
      M0[slot] = make_float4(acc[i][0].x,acc[i][0].y,acc[i][1].x,acc[i][1].y);
      M1[slot] = make_float4(acc[i][2].x,acc[i][2].y,acc[i][3].x,acc[i][3].y);
      MS[slot] = make_float2(m[i], ss[i]);
    }
  }
  __syncthreads();
  if (g == 0) {
    #pragma unroll
    for (int i = 0; i < 4; ++i) {
      float M = m[i];
      float2 oms[G-1];
      #pragma unroll
      for (int gg = 1; gg < G; ++gg) {
        oms[gg-1] = MS[(gg-1)*NB*LEN + xb + i];
        M = fmaxf(M, oms[gg-1].x);
      }
      float w0 = __builtin_amdgcn_exp2f(m[i] - M);
      float st = ss[i]*w0;
      float a[8];
      a[0]=acc[i][0].x*w0; a[1]=acc[i][0].y*w0; a[2]=acc[i][1].x*w0; a[3]=acc[i][1].y*w0;
      a[4]=acc[i][2].x*w0; a[5]=acc[i][2].y*w0; a[6]=acc[i][3].x*w0; a[7]=acc[i][3].y*w0;
      #pragma unroll
      for (int gg = 1; gg < G; ++gg) {
        int slot = (gg-1)*NB*LEN + xb + i;
        float wg = __builtin_amdgcn_exp2f(oms[gg-1].x - M);
        st += oms[gg-1].y*wg;
        float4 a0 = M0[slot];
        float4 a1 = M1[slot];
        a[0] = fmaf(a0.x, wg, a[0]); a[1] = fmaf(a0.y, wg, a[1]);
        a[2] = fmaf(a0.z, wg, a[2]); a[3] = fmaf(a0.w, wg, a[3]);
        a[4] = fmaf(a1.x, wg, a[4]); a[5] = fmaf(a1.y, wg, a[5]);
        a[6] = fmaf(a1.z, wg, a[6]); a[7] = fmaf(a1.w, wg, a[7]);
      }
      float inv = 1.0f / st;
      float* dst = out + ((size_t)(x0+i)*XS + (size_t)(n0+ni)*NS)*64 + hd*8;
      float4 lo, hi;
      lo.x = a[0]*inv; lo.y = a[1]*inv; lo.z = a[2]*inv; lo.w = a[3]*inv;
      hi.x = a[4]*inv; hi.y = a[5]*inv; hi.z = a[6]*inv; hi.w = a[7]*inv;
      if (RELUO) {
        lo.x=fmaxf(lo.x,0.f); lo.y=fmaxf(lo.y,0.f); lo.z=fmaxf(lo.z,0.f); lo.w=fmaxf(lo.w,0.f);
        hi.x=fmaxf(hi.x,0.f); hi.y=fmaxf(hi.y,0.f); hi.z=fmaxf(hi.z,0.f); hi.w=fmaxf(hi.w,0.f);
      }
      *(float4*)dst = lo;
      *((float4*)dst + 1) = hi;
    }
  }
}

// Distinct names so rocprof attributes H vs W separately.
__global__ __launch_bounds__(256, 2)
void k_attnH(const uint4* __restrict__ kvV, const uint2* __restrict__ kvK,
             const float* __restrict__ qb, const uint4* __restrict__ rqk,
             const uint4* __restrict__ rve, const float* __restrict__ lbn,
             float* __restrict__ out) {
  attn_body<256,1,4,false,128,1>(kvV, kvK, qb, rqk, rve, lbn, out);
}
__global__ __launch_bounds__(256, 2)
void k_attnW(const uint4* __restrict__ kvV, const uint2* __restrict__ kvK,
             const float* __restrict__ qb, const uint4* __restrict__ rqk,
             const uint4* __restrict__ rve, const float* __restrict__ lbn,
             float* __restrict__ out) {
  attn_body<128,2,4,true,1,128>(kvV, kvK, qb, rqk, rve, lbn, out);
}

// ---------------- conv3 + bn + residual + relu : NHWC in -> NCHW out ----------------
__global__ __launch_bounds__(256)
void k_conv3(const float* __restrict__ in, const float* __restrict__ w,
             const float* __restrict__ bn, const float* __restrict__ resid,
             float* __restrict__ out) {
  __shared__ float L[64*65];
  int tid = threadIdx.x;
  int p0 = blockIdx.x * 64;
  const float4* src = (const float4*)(in + (size_t)p0*64);
  #pragma unroll
  for (int k = 0; k < 4; ++k) {
    int f4 = tid + k*256;
    float4 v = src[f4];
    int f = f4*4; int p = f >> 6, o = f & 63;
    L[p*65+o] = v.x; L[p*65+o+1] = v.y; L[p*65+o+2] = v.z; L[p*65+o+3] = v.w;
  }
  __syncthreads();
  int lane = tid & 63;
  int wvs = __builtin_amdgcn_readfirstlane(tid >> 6);
  f32x2 xv2[32];
  #pragma unroll
  for (int c2 = 0; c2 < 32; ++c2) {
    xv2[c2].x = L[lane*65 + 2*c2];
    xv2[c2].y = L[lane*65 + 2*c2 + 1];
  }
  #pragma unroll
  for (int r = 0; r < 16; ++r) {
    int o = wvs*16 + r;
    const f32x2* wr = (const f32x2*)(w + o*64);
    f32x2 a2 = {0.f, 0.f};
    #pragma unroll
    for (int c2 = 0; c2 < 32; ++c2) a2 = wr[c2]*xv2[c2] + a2;
    float acc = a2.x + a2.y;
    float s = bn[o] * rsqrtf(bn[192+o] + EPSF);
    float val = fmaf(acc, s, fmaf(-bn[128+o], s, bn[64+o]));
    size_t idx = (size_t)o*32768 + p0 + lane;
    out[idx] = fmaxf(val + resid[idx], 0.f);
  }
}

extern "C" void kernel_launch(void* const* d_in, const int* in_sizes, int n_in,
                              void* d_out, int out_size, void* d_ws, size_t ws_size,
                              hipStream_t stream) {
  const float* x         = (const float*)d_in[0];
  const float* conv1_w   = (const float*)d_in[1];
  const float* bn1       = (const float*)d_in[2];
  const float* kqv_w_h   = (const float*)d_in[3];
  const float* kqv_bn_h  = (const float*)d_in[4];
  const float* lbn_h     = (const float*)d_in[5];
  const float* rel_h     = (const float*)d_in[6];
  const float* kqv_w_w   = (const float*)d_in[7];
  const float* kqv_bn_w  = (const float*)d_in[8];
  const float* lbn_w     = (const float*)d_in[9];
  const float* rel_w     = (const float*)d_in[10];
  const float* conv3_w   = (const float*)d_in[11];
  const float* bn3       = (const float*)d_in[12];
  float* outp = (float*)d_out;
  char* ws = (char*)d_ws;

  float* A    = (float*)(ws);                    // 8 MiB
  uint4* kvV  = (uint4*)(ws + 8388608);          // 4 MiB
  uint2* kvK  = (uint2*)(ws + 12582912);         // 2 MiB
  float* qb   = (float*)(ws + 14680064);         // 4 MiB (f32 q)
  uint4* rqkH = (uint4*)(ws + 18874368);
  uint4* rveH = (uint4*)(ws + 18882560);
  uint4* rqkW = (uint4*)(ws + 18890752);
  uint4* rveW = (uint4*)(ws + 18894848);

  // conv1 + bn1 + relu (blocks 0..511) and rel_enc packing (blocks 512,513)
  k_conv1<<<514, 256, 0, stream>>>(x, conv1_w, bn1, A,
                                   rel_h, rel_w, rqkH, rveH, rqkW, rveW);

  // axial-H: n = w (128), seq = h (256)
  k_kqv<256,128,1><<<dim3(128,4), 512, 0, stream>>>(A, kqv_w_h, kqv_bn_h, kvV, kvK, qb);
  k_attnH<<<1024, 256, 0, stream>>>(kvV, kvK, qb, rqkH, rveH, lbn_h, A);

  // axial-W: n = h (256), seq = w (128); relu fused
  k_kqv<128,1,128><<<dim3(256,2), 512, 0, stream>>>(A, kqv_w_w, kqv_bn_w, kvV, kvK, qb);
  k_attnW<<<1024, 256, 0, stream>>>(kvV, kvK, qb, rqkW, rveW, lbn_w, A);

  // conv3 + bn3 + residual + relu : A NHWC -> out NCHW
  k_conv3<<<512, 256, 0, stream>>>(A, conv3_w, bn3, x, outp);
}